// Round 1
// baseline (162.302 us; speedup 1.0000x reference)
//
#include <hip/hip_runtime.h>

#define NB 8
#define NS 2048
#define ND 128
#define NK 16

__device__ inline unsigned long long shfl_xor_u64(unsigned long long v, int mask) {
    unsigned int lo = (unsigned int)v;
    unsigned int hi = (unsigned int)(v >> 32);
    lo = __shfl_xor((int)lo, mask, 64);
    hi = __shfl_xor((int)hi, mask, 64);
    return ((unsigned long long)hi << 32) | lo;
}

__global__ __launch_bounds__(256) void knn_kernel(
    const float* __restrict__ pts,   // [B,S,3]
    const int*   __restrict__ fidx,  // [B,S,1] (int32)
    const float* __restrict__ attr,  // [B,S,D]
    float*       __restrict__ out)   // out0 [B,S,K] | out1 [B,S,K] | out2 [B,S,K,D]
{
    const int lane = threadIdx.x & 63;
    const int row  = blockIdx.x * 4 + (threadIdx.x >> 6);   // [0, B*S)
    const int b = row >> 11;        // row / 2048
    const int i = row & 2047;       // row % 2048

    const float* pb = pts + (size_t)b * NS * 3;
    const float qx = pb[i * 3 + 0];
    const float qy = pb[i * 3 + 1];
    const float qz = pb[i * 3 + 2];

    // Each lane owns 32 candidates j = t*64 + lane; key = (dist_bits<<32)|j.
    unsigned long long keys[32];
#pragma unroll
    for (int t = 0; t < 32; ++t) {
        const int j = t * 64 + lane;
        const float x = pb[j * 3 + 0];
        const float y = pb[j * 3 + 1];
        const float z = pb[j * 3 + 2];
        const float dx = __fsub_rn(qx, x);
        const float dy = __fsub_rn(qy, y);
        const float dz = __fsub_rn(qz, z);
        // exact left-to-right, no FMA contraction (matches reference arithmetic)
        float d = __fmul_rn(dx, dx);
        d = __fadd_rn(d, __fmul_rn(dy, dy));
        d = __fadd_rn(d, __fmul_rn(dz, dz));
        keys[t] = ((unsigned long long)__float_as_uint(d) << 32) | (unsigned int)j;
    }

    // 16 rounds of filtered argmin: selection order is strictly increasing in
    // key, so "key > prev" excludes exactly the already-selected ones.
    unsigned long long prev = 0;
    unsigned long long myKey = 0;      // lane k holds round-k winner
    unsigned int win[NK];              // uniform across wave
#pragma unroll
    for (int k = 0; k < NK; ++k) {
        unsigned long long mn = ~0ULL;
#pragma unroll
        for (int t = 0; t < 32; ++t) {
            const unsigned long long key = keys[t];
            const bool ok = (k == 0) || (key > prev);
            if (ok && key < mn) mn = key;
        }
#pragma unroll
        for (int off = 32; off >= 1; off >>= 1) {
            const unsigned long long o = shfl_xor_u64(mn, off);
            if (o < mn) mn = o;
        }
        prev = mn;
        win[k] = (unsigned int)mn;
        if (lane == k) myKey = mn;
    }

    float* out0 = out;                                   // [B,S,K]
    float* out1 = out + (size_t)NB * NS * NK;            // [B,S,K]
    float* out2 = out + (size_t)2 * NB * NS * NK;        // [B,S,K,D]
    const size_t rowBase = (size_t)row * NK;

    if (lane < NK) {
        const float dsel = __uint_as_float((unsigned int)(myKey >> 32));
        const unsigned int jn = (unsigned int)myKey;
        out0[rowBase + lane] = dsel;
        const int ii = fidx[(size_t)b * NS + i];
        const int jj = fidx[(size_t)b * NS + jn];
        out1[rowBase + lane] = fabsf((float)(ii - jj));
    }

    // Gather attribute rows: 2 neighbor slots per pass, 32 lanes x float4 each.
    const int half = lane >> 5;      // 0 or 1
    const int comp = lane & 31;      // float4 slot within the 128-float row
    const float* ab = attr + (size_t)b * NS * ND;
    float* o2row = out2 + rowBase * ND;
#pragma unroll
    for (int p = 0; p < 8; ++p) {
        const unsigned int j0 = win[2 * p];
        const unsigned int j1 = win[2 * p + 1];
        const unsigned int jj = half ? j1 : j0;
        const float4 v = *(const float4*)(ab + (size_t)jj * ND + comp * 4);
        const int k = 2 * p + half;
        *(float4*)(o2row + (size_t)k * ND + comp * 4) = v;
    }
}

extern "C" void kernel_launch(void* const* d_in, const int* in_sizes, int n_in,
                              void* d_out, int out_size, void* d_ws, size_t ws_size,
                              hipStream_t stream) {
    const float* pts  = (const float*)d_in[0];
    const int*   fidx = (const int*)d_in[1];
    const float* attr = (const float*)d_in[2];
    float* out = (float*)d_out;

    const int rows = NB * NS;                 // 16384
    const int blocks = rows / 4;              // 4096 blocks, 4 waves each
    knn_kernel<<<blocks, 256, 0, stream>>>(pts, fidx, attr, out);
}

// Round 2
// 64.720 us; speedup vs baseline: 2.5077x; 2.5077x over previous
//
#include <hip/hip_runtime.h>

#define NB 8
#define NS 2048
#define ND 128
#define NK 16

__device__ inline unsigned long long shfl_xor_u64(unsigned long long v, int mask) {
    unsigned int lo = (unsigned int)v;
    unsigned int hi = (unsigned int)(v >> 32);
    lo = __shfl_xor((int)lo, mask, 64);
    hi = __shfl_xor((int)hi, mask, 64);
    return ((unsigned long long)hi << 32) | lo;
}

__global__ __launch_bounds__(256) void knn_kernel(
    const float* __restrict__ pts,   // [B,S,3]
    const int*   __restrict__ fidx,  // [B,S,1] (int32)
    const float* __restrict__ attr,  // [B,S,D]
    float*       __restrict__ out)   // out0 [B,S,K] | out1 [B,S,K] | out2 [B,S,K,D]
{
    // Per-lane sorted top-16 lists; entry [16] is an OOB pad (read only after a
    // lane has already supplied 16 winners, i.e. never consumed).
    __shared__ unsigned long long sorted[4][64][17];

    const int wv   = threadIdx.x >> 6;
    const int lane = threadIdx.x & 63;
    const int row  = blockIdx.x * 4 + wv;    // [0, B*S)
    const int b = row >> 11;                 // row / 2048
    const int i = row & 2047;                // row % 2048

    const float* pb = pts + (size_t)b * NS * 3;
    const float qx = pb[i * 3 + 0];
    const float qy = pb[i * 3 + 1];
    const float qz = pb[i * 3 + 2];

    // Each lane owns 32 candidates j = t*64 + lane; key = (dist_bits<<32)|j.
    // f32 >= 0 is order-monotone as u32; low bits give the stable index
    // tie-break (matches jnp.argsort stability).
    unsigned long long keys[32];
#pragma unroll
    for (int t = 0; t < 32; ++t) {
        const int j = t * 64 + lane;
        const float x = pb[j * 3 + 0];
        const float y = pb[j * 3 + 1];
        const float z = pb[j * 3 + 2];
        const float dx = __fsub_rn(qx, x);
        const float dy = __fsub_rn(qy, y);
        const float dz = __fsub_rn(qz, z);
        // exact left-to-right, no FMA contraction (matches reference arithmetic)
        float d = __fmul_rn(dx, dx);
        d = __fadd_rn(d, __fmul_rn(dy, dy));
        d = __fadd_rn(d, __fmul_rn(dz, dz));
        keys[t] = ((unsigned long long)__float_as_uint(d) << 32) | (unsigned int)j;
    }

    // Batcher odd-even mergesort of 32 keys (191 compare-exchanges, 15
    // parallel stages -> log-depth dependency chains, all-static indices).
#pragma unroll
    for (int p = 1; p < 32; p <<= 1) {
#pragma unroll
        for (int k = p; k >= 1; k >>= 1) {
#pragma unroll
            for (int j = k & (p - 1); j + k < 32; j += 2 * k) {
#pragma unroll
                for (int ii = 0; ii < k; ++ii) {
                    const int a = ii + j;
                    const int c = ii + j + k;
                    if (c < 32 && (a / (2 * p)) == (c / (2 * p))) {
                        const unsigned long long ka = keys[a];
                        const unsigned long long kc = keys[c];
                        const bool lt = ka < kc;
                        keys[a] = lt ? ka : kc;
                        keys[c] = lt ? kc : ka;
                    }
                }
            }
        }
    }

    // Spill each lane's sorted head-16 to LDS (own-lane region only; no
    // cross-lane reads -> no barrier needed beyond lgkmcnt).
    unsigned long long* myList = &sorted[wv][lane][0];
#pragma unroll
    for (int t = 0; t < NK; ++t) myList[t] = keys[t];

    // 16-round tournament merge of the 64 sorted lists.
    unsigned long long h = keys[0];
    int hp = 0;
    unsigned long long myKey = 0;      // lane k holds round-k winner
#pragma unroll
    for (int k = 0; k < NK; ++k) {
        unsigned long long mn = h;
#pragma unroll
        for (int off = 32; off >= 1; off >>= 1) {
            const unsigned long long o = shfl_xor_u64(mn, off);
            if (o < mn) mn = o;
        }
        if (lane == k) myKey = mn;
        if (h == mn) {                 // keys globally unique -> only winner
            ++hp;
            h = myList[hp < NK ? hp : NK];
        }
    }

    float* out0 = out;                                   // [B,S,K]
    float* out1 = out + (size_t)NB * NS * NK;            // [B,S,K]
    float* out2 = out + (size_t)2 * NB * NS * NK;        // [B,S,K,D]
    const size_t rowBase = (size_t)row * NK;

    if (lane < NK) {
        const float dsel = __uint_as_float((unsigned int)(myKey >> 32));
        const unsigned int jn = (unsigned int)myKey;
        out0[rowBase + lane] = dsel;
        const int ii = fidx[(size_t)b * NS + i];
        const int jj = fidx[(size_t)b * NS + jn];
        out1[rowBase + lane] = fabsf((float)(ii - jj));
    }

    // Gather attribute rows: 2 neighbor slots per pass, 32 lanes x float4 each.
    const int half = lane >> 5;      // 0 or 1
    const int comp = lane & 31;      // float4 slot within the 128-float row
    const int myJ  = (int)(unsigned int)myKey;
    const float* ab = attr + (size_t)b * NS * ND;
    float* o2row = out2 + rowBase * ND;
#pragma unroll
    for (int p = 0; p < 8; ++p) {
        const unsigned int j0 = (unsigned int)__shfl(myJ, 2 * p, 64);
        const unsigned int j1 = (unsigned int)__shfl(myJ, 2 * p + 1, 64);
        const unsigned int jj = half ? j1 : j0;
        const float4 v = *(const float4*)(ab + (size_t)jj * ND + comp * 4);
        const int k = 2 * p + half;
        *(float4*)(o2row + (size_t)k * ND + comp * 4) = v;
    }
}

extern "C" void kernel_launch(void* const* d_in, const int* in_sizes, int n_in,
                              void* d_out, int out_size, void* d_ws, size_t ws_size,
                              hipStream_t stream) {
    const float* pts  = (const float*)d_in[0];
    const int*   fidx = (const int*)d_in[1];
    const float* attr = (const float*)d_in[2];
    float* out = (float*)d_out;

    const int rows = NB * NS;                 // 16384
    const int blocks = rows / 4;              // 4096 blocks, 4 waves each
    knn_kernel<<<blocks, 256, 0, stream>>>(pts, fidx, attr, out);
}

// Round 3
// 49.622 us; speedup vs baseline: 3.2708x; 1.3043x over previous
//
#include <hip/hip_runtime.h>

#define NB 8
#define NS 2048
#define ND 128
#define NK 16

// DPP cross-lane move of a double (both 32-bit halves). CTRL compile-time.
template <int CTRL>
__device__ inline double dpp_f64(double v) {
    long long b = __double_as_longlong(v);
    int lo = (int)(unsigned int)b;
    int hi = (int)(b >> 32);
    lo = __builtin_amdgcn_update_dpp(0, lo, CTRL, 0xF, 0xF, true);
    hi = __builtin_amdgcn_update_dpp(0, hi, CTRL, 0xF, 0xF, true);
    return __longlong_as_double(((long long)hi << 32) | (unsigned int)lo);
}

__device__ inline double shfl_xor_f64(double v, int mask) {
    long long b = __double_as_longlong(v);
    int lo = __shfl_xor((int)(unsigned int)b, mask, 64);
    int hi = __shfl_xor((int)(b >> 32), mask, 64);
    return __longlong_as_double(((long long)hi << 32) | (unsigned int)lo);
}

// min over all 64 lanes, result in every lane. xor{1,2,7,15} via DPP (VALU
// pipe), xor{16,32} via shfl (LDS pipe). Span{1,2,7,15,16,32} = 0..63.
__device__ inline double wave_min_f64(double v) {
    v = fmin(v, dpp_f64<0xB1>(v));   // quad_perm [1,0,3,2]  : xor 1
    v = fmin(v, dpp_f64<0x4E>(v));   // quad_perm [2,3,0,1]  : xor 2
    v = fmin(v, dpp_f64<0x141>(v));  // row_half_mirror      : xor 7
    v = fmin(v, dpp_f64<0x140>(v));  // row_mirror           : xor 15
    v = fmin(v, shfl_xor_f64(v, 16));
    v = fmin(v, shfl_xor_f64(v, 32));
    return v;
}

__global__ __launch_bounds__(256) void knn_kernel(
    const float* __restrict__ pts,   // [B,S,3]
    const int*   __restrict__ fidx,  // [B,S,1]
    const float* __restrict__ attr,  // [B,S,D]
    float*       __restrict__ out)   // out0 [B,S,K] | out1 [B,S,K] | out2 [B,S,K,D]
{
    // Per-lane sorted top-16 lists (+1 pad slot, written with the 17th key).
    __shared__ double sorted[4][64][17];

    const int wv   = threadIdx.x >> 6;
    const int lane = threadIdx.x & 63;
    const int row  = blockIdx.x * 4 + wv;    // [0, B*S)
    const int b = row >> 11;
    const int i = row & 2047;

    const float* pb = pts + (size_t)b * NS * 3;
    const float qx = pb[i * 3 + 0];
    const float qy = pb[i * 3 + 1];
    const float qz = pb[i * 3 + 2];

    // Monotone f64 key: bits = 0x3FF<<52 | dist_bits<<20 | j<<9.
    // Positive normal doubles in [1,2): f64 order == (dist_bits, j) lex order.
    double keys[33];
#pragma unroll
    for (int t = 0; t < 32; ++t) {
        const int j = t * 64 + lane;
        const float x = pb[j * 3 + 0];
        const float y = pb[j * 3 + 1];
        const float z = pb[j * 3 + 2];
        const float dx = __fsub_rn(qx, x);
        const float dy = __fsub_rn(qy, y);
        const float dz = __fsub_rn(qz, z);
        // exact left-to-right, no FMA contraction (matches reference arithmetic)
        float d = __fmul_rn(dx, dx);
        d = __fadd_rn(d, __fmul_rn(dy, dy));
        d = __fadd_rn(d, __fmul_rn(dz, dz));
        const unsigned int db = __float_as_uint(d);
        const unsigned int hi = 0x3FF00000u | (db >> 12);
        const unsigned int lo = (db << 20) | ((unsigned int)j << 9);
        keys[t] = __longlong_as_double(((long long)hi << 32) | lo);
    }

    // Batcher odd-even mergesort of 32 keys; CE = v_min_f64 + v_max_f64.
#pragma unroll
    for (int p = 1; p < 32; p <<= 1) {
#pragma unroll
        for (int k = p; k >= 1; k >>= 1) {
#pragma unroll
            for (int j = k & (p - 1); j + k < 32; j += 2 * k) {
#pragma unroll
                for (int ii = 0; ii < k; ++ii) {
                    const int a = ii + j;
                    const int c = ii + j + k;
                    if (c < 32 && (a / (2 * p)) == (c / (2 * p))) {
                        const double ka = keys[a];
                        const double kc = keys[c];
                        keys[a] = fmin(ka, kc);
                        keys[c] = fmax(ka, kc);
                    }
                }
            }
        }
    }

    // Spill sorted head (16 + pad) to LDS; own-lane region only.
    double* myList = &sorted[wv][lane][0];
#pragma unroll
    for (int t = 0; t <= NK; ++t) myList[t] = keys[t];

    // 16-round tournament merge of the 64 sorted lists.
    double h = keys[0];
    int hp = 0;
    double myKey = 0.0;                // lane k holds round-k winner
#pragma unroll
    for (int k = 0; k < NK; ++k) {
        const double mn = wave_min_f64(h);
        if (lane == k) myKey = mn;
        if (h == mn) {                 // keys globally unique -> single winner
            ++hp;
            h = myList[hp];
        }
    }

    float* out0 = out;                                   // [B,S,K]
    float* out1 = out + (size_t)NB * NS * NK;            // [B,S,K]
    float* out2 = out + (size_t)2 * NB * NS * NK;        // [B,S,K,D]
    const size_t rowBase = (size_t)row * NK;

    const long long kb = __double_as_longlong(myKey);
    const int myJ = (int)((kb >> 9) & 0x7FF);

    if (lane < NK) {
        const unsigned int db = (unsigned int)(kb >> 20);
        out0[rowBase + lane] = __uint_as_float(db);
        const int ii = fidx[(size_t)b * NS + i];
        const int jj = fidx[(size_t)b * NS + myJ];
        out1[rowBase + lane] = fabsf((float)(ii - jj));
    }

    // Gather attribute rows: 2 neighbor slots per pass, 32 lanes x float4 each.
    const int half = lane >> 5;      // 0 or 1
    const int comp = lane & 31;      // float4 slot within the 128-float row
    const float* ab = attr + (size_t)b * NS * ND;
    float* o2row = out2 + rowBase * ND;
#pragma unroll
    for (int p = 0; p < 8; ++p) {
        const unsigned int j0 = (unsigned int)__shfl(myJ, 2 * p, 64);
        const unsigned int j1 = (unsigned int)__shfl(myJ, 2 * p + 1, 64);
        const unsigned int jj = half ? j1 : j0;
        const float4 v = *(const float4*)(ab + (size_t)jj * ND + comp * 4);
        const int k = 2 * p + half;
        *(float4*)(o2row + (size_t)k * ND + comp * 4) = v;
    }
}

extern "C" void kernel_launch(void* const* d_in, const int* in_sizes, int n_in,
                              void* d_out, int out_size, void* d_ws, size_t ws_size,
                              hipStream_t stream) {
    const float* pts  = (const float*)d_in[0];
    const int*   fidx = (const int*)d_in[1];
    const float* attr = (const float*)d_in[2];
    float* out = (float*)d_out;

    const int rows = NB * NS;                 // 16384
    const int blocks = rows / 4;              // 4096 blocks, 4 waves each
    knn_kernel<<<blocks, 256, 0, stream>>>(pts, fidx, attr, out);
}